// Round 15
// baseline (103.814 us; speedup 1.0000x reference)
//
#include <hip/hip_runtime.h>
#include <hip/hip_bf16.h>
#include <cstdint>
#include <cstddef>

#define NB 2048
#define NT 200
#define ND 64
#define NH1 128
#define NH2 64
#define NT2 13    // 13 tiles of 16 rows = 208 >= 200
#define NWAVE 4   // 4 batch rows per 256-thread block
#define WSLICE 10752

typedef __bf16 bf16x8 __attribute__((ext_vector_type(8)));
typedef float f32x4 __attribute__((ext_vector_type(4)));

#define MFMA16(A, Bv, C) __builtin_amdgcn_mfma_f32_16x16x32_bf16((A), (Bv), (C), 0, 0, 0)

union BF8u { __bf16 b[8]; bf16x8 v; uint4 u4; };
union BF4u { __bf16 b[4]; uint2 u2; };

// prep: QpT[j][c] = (W1q+W1d)^T; AbT[j][c] = (W1k-W1d)^T; PT[j][c] = W1prod^T;
//       W2t[h2][j] = bf16(W2[j][h2])
__global__ void prep_kernel(const float* __restrict__ W1, const float* __restrict__ W2,
                            float* __restrict__ QpT, float* __restrict__ AbT,
                            float* __restrict__ PT, __bf16* __restrict__ W2t) {
    int tid = blockIdx.x * blockDim.x + threadIdx.x;
    if (tid < NH1 * ND) {
        int jj = tid >> 6, cc = tid & 63;
        QpT[tid] = W1[cc * NH1 + jj] + W1[(128 + cc) * NH1 + jj];
        AbT[tid] = W1[(64 + cc) * NH1 + jj] - W1[(128 + cc) * NH1 + jj];
        PT[tid]  = W1[(192 + cc) * NH1 + jj];
        int j2 = tid >> 7, k = tid & 127;
        W2t[tid] = (__bf16)W2[k * NH2 + j2];
    }
}

// ONE WAVE PER BATCH ROW, 4 independent waves per block, ZERO barriers.
// LDS is sliced per wave; same-wave ds ordering is compiler-enforced lgkmcnt.
// Per-wave slice (10752 B): H1[2][16][136] bf16 (8704) + QH[128] f32 (512)
//   + B2WO[128] f32 (512) + EB[2][16] f32 (128) + MB[208] f32 (832)
__global__ __launch_bounds__(256, 2)
void attn_main(const float* __restrict__ query, const float* __restrict__ key,
               const float* __restrict__ value, const int* __restrict__ mask,
               const float* __restrict__ b1, const float* __restrict__ b2,
               const float* __restrict__ Wo,
               const float* __restrict__ QpT, const float* __restrict__ AbT,
               const float* __restrict__ PT, const __bf16* __restrict__ W2t,
               float* __restrict__ out)
{
    __shared__ __align__(16) char smem[NWAVE * WSLICE];
    const int wave = threadIdx.x >> 6;
    const int lane = threadIdx.x & 63;
    char* ws = smem + wave * WSLICE;
    auto H1 = (__bf16(*)[16][136])(ws);            // [2][16][136]
    float* QH   = (float*)(ws + 8704);             // qh[128]
    float* B2WO = (float*)(ws + 9216);             // b2[64] ++ Wo[64]
    auto EB = (float(*)[16])(ws + 9728);           // e broadcast, dbuf
    float* MB = (float*)(ws + 9856);               // maskf[208]

    const int b = blockIdx.x * NWAVE + wave;
    const int jn = lane & 15;
    const int g4 = lane >> 4;
    const int g8 = g4 * 8;

    const float* kb = key + (size_t)b * NT * ND;
    const float* vb = value + (size_t)b * NT * ND;

    // ---- k tile 0 prefetch (B-frag gather: lane reads k[t=jn][c=32kk+g8+e]) ----
    float4 pf0, pf1, pf2, pf3;
    {
        const float* p = kb + jn * ND + g8;
        pf0 = *(const float4*)(p);
        pf1 = *(const float4*)(p + 4);
        pf2 = *(const float4*)(p + 32);
        pf3 = *(const float4*)(p + 36);
    }
    // ---- V tile 0 prefetch: lane (jn,g4) owns d=4jn..4jn+4, rows 4g4+u ----
    float4 vv0, vv1, vv2, vv3;
    vv0 = *(const float4*)(vb + (size_t)(4 * g4 + 0) * ND + 4 * jn);
    vv1 = *(const float4*)(vb + (size_t)(4 * g4 + 1) * ND + 4 * jn);
    vv2 = *(const float4*)(vb + (size_t)(4 * g4 + 2) * ND + 4 * jn);
    vv3 = *(const float4*)(vb + (size_t)(4 * g4 + 3) * ND + 4 * jn);

    // ---- mask -> LDS floats (once) ----
    #pragma unroll
    for (int i = 0; i < 4; ++i) {
        const int t = lane + 64 * i;
        if (t < 208) {
            const int tc = t < NT ? t : NT - 1;
            MB[t] = (t < NT && mask[(size_t)b * NT + tc] != 0) ? 1.f : 0.f;
        }
    }

    // ---- q values (c = 32kk + g8 + e), jn-independent -> column-replicated ----
    const float* qp = query + (size_t)b * ND;
    const float4 qa0 = *(const float4*)(qp + g8);
    const float4 qa1 = *(const float4*)(qp + g8 + 4);
    const float4 qb0 = *(const float4*)(qp + 32 + g8);
    const float4 qb1 = *(const float4*)(qp + 32 + g8 + 4);
    bf16x8 qfrag0, qfrag1;
    {
        BF8u u;
        u.b[0]=(__bf16)qa0.x; u.b[1]=(__bf16)qa0.y; u.b[2]=(__bf16)qa0.z; u.b[3]=(__bf16)qa0.w;
        u.b[4]=(__bf16)qa1.x; u.b[5]=(__bf16)qa1.y; u.b[6]=(__bf16)qa1.z; u.b[7]=(__bf16)qa1.w;
        qfrag0 = u.v;
        u.b[0]=(__bf16)qb0.x; u.b[1]=(__bf16)qb0.y; u.b[2]=(__bf16)qb0.z; u.b[3]=(__bf16)qb0.w;
        u.b[4]=(__bf16)qb1.x; u.b[5]=(__bf16)qb1.y; u.b[6]=(__bf16)qb1.z; u.b[7]=(__bf16)qb1.w;
        qfrag1 = u.v;
    }

    // ---- W2^T A-fragments, all held in registers (16 frags) ----
    bf16x8 w2f[4][4];
    #pragma unroll
    for (int ht = 0; ht < 4; ++ht)
        #pragma unroll
        for (int kk = 0; kk < 4; ++kk)
            w2f[ht][kk] = *(const bf16x8*)(W2t + (16 * ht + jn) * NH1 + 32 * kk + g8);

    // ---- qh via prologue MFMA: C[j][t] = (QpT @ q_replicated)[j] = qh[j] ----
    #pragma unroll
    for (int n = 0; n < 8; ++n) {
        bf16x8 qpt0, qpt1;
        {
            const float* p = QpT + (16 * n + jn) * ND + g8;
            const float4 a0 = *(const float4*)(p);
            const float4 a1 = *(const float4*)(p + 4);
            const float4 a2 = *(const float4*)(p + 32);
            const float4 a3 = *(const float4*)(p + 36);
            BF8u u;
            u.b[0]=(__bf16)a0.x; u.b[1]=(__bf16)a0.y; u.b[2]=(__bf16)a0.z; u.b[3]=(__bf16)a0.w;
            u.b[4]=(__bf16)a1.x; u.b[5]=(__bf16)a1.y; u.b[6]=(__bf16)a1.z; u.b[7]=(__bf16)a1.w;
            qpt0 = u.v;
            u.b[0]=(__bf16)a2.x; u.b[1]=(__bf16)a2.y; u.b[2]=(__bf16)a2.z; u.b[3]=(__bf16)a2.w;
            u.b[4]=(__bf16)a3.x; u.b[5]=(__bf16)a3.y; u.b[6]=(__bf16)a3.z; u.b[7]=(__bf16)a3.w;
            qpt1 = u.v;
        }
        f32x4 aq = {0.f, 0.f, 0.f, 0.f};
        aq = MFMA16(qpt0, qfrag0, aq);
        aq = MFMA16(qpt1, qfrag1, aq);
        const float4 b1v = *(const float4*)(b1 + 16 * n + 4 * g4);
        if (jn == 0) {
            float4 qv{aq[0] + b1v.x, aq[1] + b1v.y, aq[2] + b1v.z, aq[3] + b1v.w};
            *(float4*)(QH + 16 * n + 4 * g4) = qv;
        }
    }

    // ---- stage b2 / Wo into LDS (per-wave copy) ----
    B2WO[lane] = b2[lane];
    B2WO[64 + lane] = Wo[lane];

    // ---- GEMM1 A-frags: B_b^T[j][c] = AbT + q[c]*PT, all 16 held ----
    bf16x8 g1_b[8][2];
    #pragma unroll
    for (int n = 0; n < 8; ++n) {
        #pragma unroll
        for (int kk = 0; kk < 2; ++kk) {
            const float* ab = AbT + (16 * n + jn) * ND + 32 * kk + g8;
            const float* pt = PT  + (16 * n + jn) * ND + 32 * kk + g8;
            const float4 a0 = *(const float4*)(ab);
            const float4 a1 = *(const float4*)(ab + 4);
            const float4 p0 = *(const float4*)(pt);
            const float4 p1 = *(const float4*)(pt + 4);
            const float qv[8] = {
                kk ? qb0.x : qa0.x, kk ? qb0.y : qa0.y, kk ? qb0.z : qa0.z, kk ? qb0.w : qa0.w,
                kk ? qb1.x : qa1.x, kk ? qb1.y : qa1.y, kk ? qb1.z : qa1.z, kk ? qb1.w : qa1.w};
            const float av[8] = {a0.x,a0.y,a0.z,a0.w,a1.x,a1.y,a1.z,a1.w};
            const float pv[8] = {p0.x,p0.y,p0.z,p0.w,p1.x,p1.y,p1.z,p1.w};
            BF8u vh;
            #pragma unroll
            for (int e = 0; e < 8; ++e)
                vh.b[e] = (__bf16)fmaf(qv[e], pv[e], av[e]);
            g1_b[n][kk] = vh.v;
        }
    }

    // ---- main loop: 13 tiles of 16 t-rows, fully unrolled, ZERO barriers ----
    float O0 = 0.f, O1 = 0.f, O2 = 0.f, O3 = 0.f, den = 0.f;
    #pragma unroll
    for (int ti = 0; ti < NT2; ++ti) {
        const int t0 = ti * 16;
        const int buf = ti & 1;

        // convert current k tile to B-frags
        bf16x8 kf0, kf1;
        {
            BF8u u;
            u.b[0]=(__bf16)pf0.x; u.b[1]=(__bf16)pf0.y; u.b[2]=(__bf16)pf0.z; u.b[3]=(__bf16)pf0.w;
            u.b[4]=(__bf16)pf1.x; u.b[5]=(__bf16)pf1.y; u.b[6]=(__bf16)pf1.z; u.b[7]=(__bf16)pf1.w;
            kf0 = u.v;
            u.b[0]=(__bf16)pf2.x; u.b[1]=(__bf16)pf2.y; u.b[2]=(__bf16)pf2.z; u.b[3]=(__bf16)pf2.w;
            u.b[4]=(__bf16)pf3.x; u.b[5]=(__bf16)pf3.y; u.b[6]=(__bf16)pf3.z; u.b[7]=(__bf16)pf3.w;
            kf1 = u.v;
        }
        // issue next k tile (lands under this tile's compute)
        if (ti + 1 < NT2) {
            int t = t0 + 16 + jn;
            t = t < NT ? t : NT - 1;
            const float* p = kb + (size_t)t * ND + g8;
            pf0 = *(const float4*)(p);
            pf1 = *(const float4*)(p + 4);
            pf2 = *(const float4*)(p + 32);
            pf3 = *(const float4*)(p + 36);
        }

        // GEMM1: h1^T(ti) = B_b^T @ k^T  -> relu(+qh) -> H1[buf]
        #pragma unroll
        for (int n = 0; n < 8; ++n) {
            f32x4 ac = {0.f, 0.f, 0.f, 0.f};
            ac = MFMA16(g1_b[n][0], kf0, ac);
            ac = MFMA16(g1_b[n][1], kf1, ac);
            const float4 qv = *(const float4*)(QH + 16 * n + 4 * g4);
            BF4u pk;
            pk.b[0] = (__bf16)fmaxf(ac[0] + qv.x, 0.f);
            pk.b[1] = (__bf16)fmaxf(ac[1] + qv.y, 0.f);
            pk.b[2] = (__bf16)fmaxf(ac[2] + qv.z, 0.f);
            pk.b[3] = (__bf16)fmaxf(ac[3] + qv.w, 0.f);
            *(uint2*)(&H1[buf][jn][16 * n + 4 * g4]) = pk.u2;
        }

        // GEMM2: C2[h2][t] = W2^T @ h1  (h1 B-frags from wave-private LDS)
        bf16x8 hf[4];
        #pragma unroll
        for (int kk = 0; kk < 4; ++kk)
            hf[kk] = *(const bf16x8*)(&H1[buf][jn][32 * kk + g8]);
        f32x4 a2[4];
        #pragma unroll
        for (int ht = 0; ht < 4; ++ht) {
            f32x4 ac = {0.f, 0.f, 0.f, 0.f};
            ac = MFMA16(w2f[ht][0], hf[0], ac);
            ac = MFMA16(w2f[ht][1], hf[1], ac);
            ac = MFMA16(w2f[ht][2], hf[2], ac);
            ac = MFMA16(w2f[ht][3], hf[3], ac);
            a2[ht] = ac;
        }

        // score s[t=jn] = sum_h2 relu(C2 + b2) * Wo ; reduce over g4-lanes
        float sp = 0.f;
        #pragma unroll
        for (int ht = 0; ht < 4; ++ht) {
            const float4 bv = *(const float4*)(B2WO + 16 * ht + 4 * g4);
            const float4 wv = *(const float4*)(B2WO + 64 + 16 * ht + 4 * g4);
            sp += fmaxf(a2[ht][0] + bv.x, 0.f) * wv.x;
            sp += fmaxf(a2[ht][1] + bv.y, 0.f) * wv.y;
            sp += fmaxf(a2[ht][2] + bv.z, 0.f) * wv.z;
            sp += fmaxf(a2[ht][3] + bv.w, 0.f) * wv.w;
        }
        sp += __shfl_xor(sp, 16);
        sp += __shfl_xor(sp, 32);

        const float e = MB[t0 + jn] * __expf(sp);
        den += e;
        if (lane < 16) EB[buf][jn] = e;

        // V accumulate with PREFETCHED vv (loaded during previous tile)
        {
            const float e0 = EB[buf][4 * g4 + 0];
            const float e1 = EB[buf][4 * g4 + 1];
            const float e2 = EB[buf][4 * g4 + 2];
            const float e3 = EB[buf][4 * g4 + 3];
            O0 = fmaf(e0, vv0.x, O0); O1 = fmaf(e0, vv0.y, O1);
            O2 = fmaf(e0, vv0.z, O2); O3 = fmaf(e0, vv0.w, O3);
            O0 = fmaf(e1, vv1.x, O0); O1 = fmaf(e1, vv1.y, O1);
            O2 = fmaf(e1, vv1.z, O2); O3 = fmaf(e1, vv1.w, O3);
            O0 = fmaf(e2, vv2.x, O0); O1 = fmaf(e2, vv2.y, O1);
            O2 = fmaf(e2, vv2.z, O2); O3 = fmaf(e2, vv2.w, O3);
            O0 = fmaf(e3, vv3.x, O0); O1 = fmaf(e3, vv3.y, O1);
            O2 = fmaf(e3, vv3.z, O2); O3 = fmaf(e3, vv3.w, O3);
        }
        // issue V loads for tile ti+1 (after last use of vv -> WAR-safe,
        // lands under tile ti+1's GEMM1+GEMM2)
        if (ti + 1 < NT2) {
            int tv0 = t0 + 16 + 4 * g4 + 0; tv0 = tv0 < NT ? tv0 : NT - 1;
            int tv1 = t0 + 16 + 4 * g4 + 1; tv1 = tv1 < NT ? tv1 : NT - 1;
            int tv2 = t0 + 16 + 4 * g4 + 2; tv2 = tv2 < NT ? tv2 : NT - 1;
            int tv3 = t0 + 16 + 4 * g4 + 3; tv3 = tv3 < NT ? tv3 : NT - 1;
            vv0 = *(const float4*)(vb + (size_t)tv0 * ND + 4 * jn);
            vv1 = *(const float4*)(vb + (size_t)tv1 * ND + 4 * jn);
            vv2 = *(const float4*)(vb + (size_t)tv2 * ND + 4 * jn);
            vv3 = *(const float4*)(vb + (size_t)tv3 * ND + 4 * jn);
        }
    }

    // ---- final reduces (wave-local) + store ----
    O0 += __shfl_xor(O0, 16); O0 += __shfl_xor(O0, 32);
    O1 += __shfl_xor(O1, 16); O1 += __shfl_xor(O1, 32);
    O2 += __shfl_xor(O2, 16); O2 += __shfl_xor(O2, 32);
    O3 += __shfl_xor(O3, 16); O3 += __shfl_xor(O3, 32);
    den += __shfl_xor(den, 1);
    den += __shfl_xor(den, 2);
    den += __shfl_xor(den, 4);
    den += __shfl_xor(den, 8);
    if (lane < 16) {
        const float inv = 1.f / den;
        float4 o{O0 * inv, O1 * inv, O2 * inv, O3 * inv};
        *(float4*)(out + (size_t)b * ND + 4 * jn) = o;
    }
}

extern "C" void kernel_launch(void* const* d_in, const int* in_sizes, int n_in,
                              void* d_out, int out_size, void* d_ws, size_t ws_size,
                              hipStream_t stream) {
    const float* query = (const float*)d_in[0];
    const float* key   = (const float*)d_in[1];
    const float* value = (const float*)d_in[2];
    const int*   maskp = (const int*)d_in[3];
    const float* W1    = (const float*)d_in[4];
    const float* b1    = (const float*)d_in[5];
    const float* W2    = (const float*)d_in[6];
    const float* b2    = (const float*)d_in[7];
    const float* Wo    = (const float*)d_in[8];
    float* out = (float*)d_out;

    float* QpT = (float*)d_ws;                 // 128*64 f32
    float* AbT = QpT + NH1 * ND;               // 128*64 f32
    float* PT  = AbT + NH1 * ND;               // 128*64 f32
    __bf16* W2t = (__bf16*)(PT + NH1 * ND);    // 64*128 bf16

    prep_kernel<<<32, 256, 0, stream>>>(W1, W2, QpT, AbT, PT, W2t);
    attn_main<<<NB / NWAVE, 64 * NWAVE, 0, stream>>>(query, key, value, maskp,
                                                     b1, b2, Wo,
                                                     QpT, AbT, PT, W2t, out);
}

// Round 16
// 71.896 us; speedup vs baseline: 1.4440x; 1.4440x over previous
//
#include <hip/hip_runtime.h>
#include <hip/hip_bf16.h>
#include <cstdint>
#include <cstddef>

#define NB 2048
#define NT 200
#define ND 64
#define NH1 128
#define NH2 64
#define NT2 13   // 13 tiles of 16 rows = 208 >= 200

typedef __bf16 bf16x8 __attribute__((ext_vector_type(8)));
typedef float f32x4 __attribute__((ext_vector_type(4)));

#define MFMA16(A, Bv, C) __builtin_amdgcn_mfma_f32_16x16x32_bf16((A), (Bv), (C), 0, 0, 0)

union BF8u { __bf16 b[8]; bf16x8 v; uint4 u4; };
union BF4u { __bf16 b[4]; uint2 u2; };

// prep: QpT[j][c] = (W1q+W1d)^T; AbT[j][c] = (W1k-W1d)^T; PT[j][c] = W1prod^T;
//       W2t[h2][j] = bf16(W2[j][h2])
__global__ void prep_kernel(const float* __restrict__ W1, const float* __restrict__ W2,
                            float* __restrict__ QpT, float* __restrict__ AbT,
                            float* __restrict__ PT, __bf16* __restrict__ W2t) {
    int tid = blockIdx.x * blockDim.x + threadIdx.x;
    if (tid < NH1 * ND) {
        int jj = tid >> 6, cc = tid & 63;
        QpT[tid] = W1[cc * NH1 + jj] + W1[(128 + cc) * NH1 + jj];
        AbT[tid] = W1[(64 + cc) * NH1 + jj] - W1[(128 + cc) * NH1 + jj];
        PT[tid]  = W1[(192 + cc) * NH1 + jj];
        int j2 = tid >> 7, k = tid & 127;
        W2t[tid] = (__bf16)W2[k * NH2 + j2];
    }
}

// ONE WAVE PER BATCH ROW (64-thread blocks), ZERO barriers; LDS wave-private.
// __launch_bounds__(64,1): 256-VGPR budget (allocator rule: budget=256/minwaves).
// Grid = 2048 waves = 2 waves/SIMD, which HW permits at VGPR<=256 -> no
// occupancy cost from the high budget.
// LDS (10688 B): H1[2][16][136] bf16 (8704) + QH[128] f32 (512)
//   + B2WO[128] f32 (512) + EB[2][16] f32 (128) + MB[208] f32 (832)
__global__ __launch_bounds__(64, 1)
void attn_main(const float* __restrict__ query, const float* __restrict__ key,
               const float* __restrict__ value, const int* __restrict__ mask,
               const float* __restrict__ b1, const float* __restrict__ b2,
               const float* __restrict__ Wo,
               const float* __restrict__ QpT, const float* __restrict__ AbT,
               const float* __restrict__ PT, const __bf16* __restrict__ W2t,
               float* __restrict__ out)
{
    __shared__ __align__(16) char smem[10688];
    auto H1 = (__bf16(*)[16][136])(smem);          // [2][16][136]
    float* QH   = (float*)(smem + 8704);           // qh[128]
    float* B2WO = (float*)(smem + 9216);           // b2[64] ++ Wo[64]
    auto EB = (float(*)[16])(smem + 9728);         // e broadcast, dbuf
    float* MB = (float*)(smem + 9856);             // maskf[208]

    const int b = blockIdx.x;
    const int lane = threadIdx.x;
    const int jn = lane & 15;
    const int g4 = lane >> 4;
    const int g8 = g4 * 8;

    const float* kb = key + (size_t)b * NT * ND;
    const float* vb = value + (size_t)b * NT * ND;

    // ---- k tile 0 prefetch (B-frag gather: lane reads k[t=jn][c=32kk+g8+e]) ----
    float4 pf0, pf1, pf2, pf3;
    {
        const float* p = kb + jn * ND + g8;
        pf0 = *(const float4*)(p);
        pf1 = *(const float4*)(p + 4);
        pf2 = *(const float4*)(p + 32);
        pf3 = *(const float4*)(p + 36);
    }
    // ---- V tile 0 prefetch: lane (jn,g4) owns d=4jn..4jn+4, rows 4g4+u ----
    float4 vv0, vv1, vv2, vv3;
    vv0 = *(const float4*)(vb + (size_t)(4 * g4 + 0) * ND + 4 * jn);
    vv1 = *(const float4*)(vb + (size_t)(4 * g4 + 1) * ND + 4 * jn);
    vv2 = *(const float4*)(vb + (size_t)(4 * g4 + 2) * ND + 4 * jn);
    vv3 = *(const float4*)(vb + (size_t)(4 * g4 + 3) * ND + 4 * jn);

    // ---- mask -> LDS floats (once) ----
    #pragma unroll
    for (int i = 0; i < 4; ++i) {
        const int t = lane + 64 * i;
        if (t < 208)
            MB[t] = (t < NT && mask[(size_t)b * NT + (t < NT ? t : NT - 1)] != 0) ? 1.f : 0.f;
    }

    // ---- q values (c = 32kk + g8 + e), jn-independent -> column-replicated ----
    const float* qp = query + (size_t)b * ND;
    const float4 qa0 = *(const float4*)(qp + g8);
    const float4 qa1 = *(const float4*)(qp + g8 + 4);
    const float4 qb0 = *(const float4*)(qp + 32 + g8);
    const float4 qb1 = *(const float4*)(qp + 32 + g8 + 4);
    bf16x8 qfrag0, qfrag1;
    {
        BF8u u;
        u.b[0]=(__bf16)qa0.x; u.b[1]=(__bf16)qa0.y; u.b[2]=(__bf16)qa0.z; u.b[3]=(__bf16)qa0.w;
        u.b[4]=(__bf16)qa1.x; u.b[5]=(__bf16)qa1.y; u.b[6]=(__bf16)qa1.z; u.b[7]=(__bf16)qa1.w;
        qfrag0 = u.v;
        u.b[0]=(__bf16)qb0.x; u.b[1]=(__bf16)qb0.y; u.b[2]=(__bf16)qb0.z; u.b[3]=(__bf16)qb0.w;
        u.b[4]=(__bf16)qb1.x; u.b[5]=(__bf16)qb1.y; u.b[6]=(__bf16)qb1.z; u.b[7]=(__bf16)qb1.w;
        qfrag1 = u.v;
    }

    // ---- W2^T A-fragments, all held in registers (16 frags) ----
    bf16x8 w2f[4][4];
    #pragma unroll
    for (int ht = 0; ht < 4; ++ht)
        #pragma unroll
        for (int kk = 0; kk < 4; ++kk)
            w2f[ht][kk] = *(const bf16x8*)(W2t + (16 * ht + jn) * NH1 + 32 * kk + g8);

    // ---- qh via prologue MFMA: C[j][t] = (QpT @ q_replicated)[j] = qh[j] ----
    #pragma unroll
    for (int n = 0; n < 8; ++n) {
        bf16x8 qpt0, qpt1;
        {
            const float* p = QpT + (16 * n + jn) * ND + g8;
            const float4 a0 = *(const float4*)(p);
            const float4 a1 = *(const float4*)(p + 4);
            const float4 a2 = *(const float4*)(p + 32);
            const float4 a3 = *(const float4*)(p + 36);
            BF8u u;
            u.b[0]=(__bf16)a0.x; u.b[1]=(__bf16)a0.y; u.b[2]=(__bf16)a0.z; u.b[3]=(__bf16)a0.w;
            u.b[4]=(__bf16)a1.x; u.b[5]=(__bf16)a1.y; u.b[6]=(__bf16)a1.z; u.b[7]=(__bf16)a1.w;
            qpt0 = u.v;
            u.b[0]=(__bf16)a2.x; u.b[1]=(__bf16)a2.y; u.b[2]=(__bf16)a2.z; u.b[3]=(__bf16)a2.w;
            u.b[4]=(__bf16)a3.x; u.b[5]=(__bf16)a3.y; u.b[6]=(__bf16)a3.z; u.b[7]=(__bf16)a3.w;
            qpt1 = u.v;
        }
        f32x4 aq = {0.f, 0.f, 0.f, 0.f};
        aq = MFMA16(qpt0, qfrag0, aq);
        aq = MFMA16(qpt1, qfrag1, aq);
        const float4 b1v = *(const float4*)(b1 + 16 * n + 4 * g4);
        if (jn == 0) {
            float4 qv{aq[0] + b1v.x, aq[1] + b1v.y, aq[2] + b1v.z, aq[3] + b1v.w};
            *(float4*)(QH + 16 * n + 4 * g4) = qv;
        }
    }

    // ---- stage b2 / Wo into LDS ----
    B2WO[lane] = b2[lane];
    B2WO[64 + lane] = Wo[lane];

    // ---- GEMM1 A-frags: B_b^T[j][c] = AbT + q[c]*PT, all 16 held ----
    bf16x8 g1_b[8][2];
    #pragma unroll
    for (int n = 0; n < 8; ++n) {
        #pragma unroll
        for (int kk = 0; kk < 2; ++kk) {
            const float* ab = AbT + (16 * n + jn) * ND + 32 * kk + g8;
            const float* pt = PT  + (16 * n + jn) * ND + 32 * kk + g8;
            const float4 a0 = *(const float4*)(ab);
            const float4 a1 = *(const float4*)(ab + 4);
            const float4 p0 = *(const float4*)(pt);
            const float4 p1 = *(const float4*)(pt + 4);
            const float qv[8] = {
                kk ? qb0.x : qa0.x, kk ? qb0.y : qa0.y, kk ? qb0.z : qa0.z, kk ? qb0.w : qa0.w,
                kk ? qb1.x : qa1.x, kk ? qb1.y : qa1.y, kk ? qb1.z : qa1.z, kk ? qb1.w : qa1.w};
            const float av[8] = {a0.x,a0.y,a0.z,a0.w,a1.x,a1.y,a1.z,a1.w};
            const float pv[8] = {p0.x,p0.y,p0.z,p0.w,p1.x,p1.y,p1.z,p1.w};
            BF8u vh;
            #pragma unroll
            for (int e = 0; e < 8; ++e)
                vh.b[e] = (__bf16)fmaf(qv[e], pv[e], av[e]);
            g1_b[n][kk] = vh.v;
        }
    }

    // ---- main loop: 13 tiles of 16 t-rows, fully unrolled, ZERO barriers ----
    float O0 = 0.f, O1 = 0.f, O2 = 0.f, O3 = 0.f, den = 0.f;
    #pragma unroll
    for (int ti = 0; ti < NT2; ++ti) {
        const int t0 = ti * 16;
        const int buf = ti & 1;

        // convert current k tile to B-frags
        bf16x8 kf0, kf1;
        {
            BF8u u;
            u.b[0]=(__bf16)pf0.x; u.b[1]=(__bf16)pf0.y; u.b[2]=(__bf16)pf0.z; u.b[3]=(__bf16)pf0.w;
            u.b[4]=(__bf16)pf1.x; u.b[5]=(__bf16)pf1.y; u.b[6]=(__bf16)pf1.z; u.b[7]=(__bf16)pf1.w;
            kf0 = u.v;
            u.b[0]=(__bf16)pf2.x; u.b[1]=(__bf16)pf2.y; u.b[2]=(__bf16)pf2.z; u.b[3]=(__bf16)pf2.w;
            u.b[4]=(__bf16)pf3.x; u.b[5]=(__bf16)pf3.y; u.b[6]=(__bf16)pf3.z; u.b[7]=(__bf16)pf3.w;
            kf1 = u.v;
        }
        // issue next k tile (lands under this tile's compute)
        if (ti + 1 < NT2) {
            int t = t0 + 16 + jn;
            t = t < NT ? t : NT - 1;
            const float* p = kb + (size_t)t * ND + g8;
            pf0 = *(const float4*)(p);
            pf1 = *(const float4*)(p + 4);
            pf2 = *(const float4*)(p + 32);
            pf3 = *(const float4*)(p + 36);
        }

        // GEMM1: h1^T(ti) = B_b^T @ k^T  -> relu(+qh) -> H1[buf]
        #pragma unroll
        for (int n = 0; n < 8; ++n) {
            f32x4 ac = {0.f, 0.f, 0.f, 0.f};
            ac = MFMA16(g1_b[n][0], kf0, ac);
            ac = MFMA16(g1_b[n][1], kf1, ac);
            const float4 qv = *(const float4*)(QH + 16 * n + 4 * g4);
            BF4u pk;
            pk.b[0] = (__bf16)fmaxf(ac[0] + qv.x, 0.f);
            pk.b[1] = (__bf16)fmaxf(ac[1] + qv.y, 0.f);
            pk.b[2] = (__bf16)fmaxf(ac[2] + qv.z, 0.f);
            pk.b[3] = (__bf16)fmaxf(ac[3] + qv.w, 0.f);
            *(uint2*)(&H1[buf][jn][16 * n + 4 * g4]) = pk.u2;
        }

        // GEMM2: C2[h2][t] = W2^T @ h1  (h1 B-frags from wave-private LDS)
        bf16x8 hf[4];
        #pragma unroll
        for (int kk = 0; kk < 4; ++kk)
            hf[kk] = *(const bf16x8*)(&H1[buf][jn][32 * kk + g8]);
        f32x4 a2[4];
        #pragma unroll
        for (int ht = 0; ht < 4; ++ht) {
            f32x4 ac = {0.f, 0.f, 0.f, 0.f};
            ac = MFMA16(w2f[ht][0], hf[0], ac);
            ac = MFMA16(w2f[ht][1], hf[1], ac);
            ac = MFMA16(w2f[ht][2], hf[2], ac);
            ac = MFMA16(w2f[ht][3], hf[3], ac);
            a2[ht] = ac;
        }

        // score s[t=jn] = sum_h2 relu(C2 + b2) * Wo ; reduce over g4-lanes
        float sp = 0.f;
        #pragma unroll
        for (int ht = 0; ht < 4; ++ht) {
            const float4 bv = *(const float4*)(B2WO + 16 * ht + 4 * g4);
            const float4 wv = *(const float4*)(B2WO + 64 + 16 * ht + 4 * g4);
            sp += fmaxf(a2[ht][0] + bv.x, 0.f) * wv.x;
            sp += fmaxf(a2[ht][1] + bv.y, 0.f) * wv.y;
            sp += fmaxf(a2[ht][2] + bv.z, 0.f) * wv.z;
            sp += fmaxf(a2[ht][3] + bv.w, 0.f) * wv.w;
        }
        sp += __shfl_xor(sp, 16);
        sp += __shfl_xor(sp, 32);

        const float e = MB[t0 + jn] * __expf(sp);
        den += e;
        if (lane < 16) EB[buf][jn] = e;

        // V accumulate with PREFETCHED vv (loaded during previous tile)
        {
            const float e0 = EB[buf][4 * g4 + 0];
            const float e1 = EB[buf][4 * g4 + 1];
            const float e2 = EB[buf][4 * g4 + 2];
            const float e3 = EB[buf][4 * g4 + 3];
            O0 = fmaf(e0, vv0.x, O0); O1 = fmaf(e0, vv0.y, O1);
            O2 = fmaf(e0, vv0.z, O2); O3 = fmaf(e0, vv0.w, O3);
            O0 = fmaf(e1, vv1.x, O0); O1 = fmaf(e1, vv1.y, O1);
            O2 = fmaf(e1, vv1.z, O2); O3 = fmaf(e1, vv1.w, O3);
            O0 = fmaf(e2, vv2.x, O0); O1 = fmaf(e2, vv2.y, O1);
            O2 = fmaf(e2, vv2.z, O2); O3 = fmaf(e2, vv2.w, O3);
            O0 = fmaf(e3, vv3.x, O0); O1 = fmaf(e3, vv3.y, O1);
            O2 = fmaf(e3, vv3.z, O2); O3 = fmaf(e3, vv3.w, O3);
        }
        // issue V loads for tile ti+1 (after last vv use -> WAR-safe; lands
        // under tile ti+1's GEMM1+GEMM2+score)
        if (ti + 1 < NT2) {
            int tv0 = t0 + 16 + 4 * g4 + 0; tv0 = tv0 < NT ? tv0 : NT - 1;
            int tv1 = t0 + 16 + 4 * g4 + 1; tv1 = tv1 < NT ? tv1 : NT - 1;
            int tv2 = t0 + 16 + 4 * g4 + 2; tv2 = tv2 < NT ? tv2 : NT - 1;
            int tv3 = t0 + 16 + 4 * g4 + 3; tv3 = tv3 < NT ? tv3 : NT - 1;
            vv0 = *(const float4*)(vb + (size_t)tv0 * ND + 4 * jn);
            vv1 = *(const float4*)(vb + (size_t)tv1 * ND + 4 * jn);
            vv2 = *(const float4*)(vb + (size_t)tv2 * ND + 4 * jn);
            vv3 = *(const float4*)(vb + (size_t)tv3 * ND + 4 * jn);
        }
    }

    // ---- final reduces (wave-local) + store ----
    O0 += __shfl_xor(O0, 16); O0 += __shfl_xor(O0, 32);
    O1 += __shfl_xor(O1, 16); O1 += __shfl_xor(O1, 32);
    O2 += __shfl_xor(O2, 16); O2 += __shfl_xor(O2, 32);
    O3 += __shfl_xor(O3, 16); O3 += __shfl_xor(O3, 32);
    den += __shfl_xor(den, 1);
    den += __shfl_xor(den, 2);
    den += __shfl_xor(den, 4);
    den += __shfl_xor(den, 8);
    if (lane < 16) {
        const float inv = 1.f / den;
        float4 o{O0 * inv, O1 * inv, O2 * inv, O3 * inv};
        *(float4*)(out + (size_t)b * ND + 4 * jn) = o;
    }
}

extern "C" void kernel_launch(void* const* d_in, const int* in_sizes, int n_in,
                              void* d_out, int out_size, void* d_ws, size_t ws_size,
                              hipStream_t stream) {
    const float* query = (const float*)d_in[0];
    const float* key   = (const float*)d_in[1];
    const float* value = (const float*)d_in[2];
    const int*   maskp = (const int*)d_in[3];
    const float* W1    = (const float*)d_in[4];
    const float* b1    = (const float*)d_in[5];
    const float* W2    = (const float*)d_in[6];
    const float* b2    = (const float*)d_in[7];
    const float* Wo    = (const float*)d_in[8];
    float* out = (float*)d_out;

    float* QpT = (float*)d_ws;                 // 128*64 f32
    float* AbT = QpT + NH1 * ND;               // 128*64 f32
    float* PT  = AbT + NH1 * ND;               // 128*64 f32
    __bf16* W2t = (__bf16*)(PT + NH1 * ND);    // 64*128 bf16

    prep_kernel<<<32, 256, 0, stream>>>(W1, W2, QpT, AbT, PT, W2t);
    attn_main<<<NB, 64, 0, stream>>>(query, key, value, maskp, b1, b2, Wo,
                                     QpT, AbT, PT, W2t, out);
}

// Round 17
// 54.752 us; speedup vs baseline: 1.8961x; 1.3131x over previous
//
#include <hip/hip_runtime.h>
#include <hip/hip_bf16.h>
#include <cstdint>
#include <cstddef>

#define NB 2048
#define NT 200
#define ND 64
#define NH1 128
#define NH2 64
#define NTILES 7
#define NTP 224

typedef __bf16 bf16x8 __attribute__((ext_vector_type(8)));
typedef float f32x4 __attribute__((ext_vector_type(4)));

#define MFMA16(A, Bv, C) __builtin_amdgcn_mfma_f32_16x16x32_bf16((A), (Bv), (C), 0, 0, 0)

union BF8u { __bf16 b[8]; bf16x8 v; uint4 u4; };
union BF4u { __bf16 b[4]; uint2 u2; };

// sum over the 16-lane DPP row (circulant rotate-add); result in every lane
template<int N>
__device__ __forceinline__ float row_ror_add(float v) {
    int r = __builtin_amdgcn_update_dpp(0, __builtin_bit_cast(int, v),
                                        0x120 | N, 0xF, 0xF, false);
    return v + __builtin_bit_cast(float, r);
}

// Raw workgroup barrier: drains LDS ops (visibility) but NOT global loads,
// so register-resident prefetches stay in flight across it. (rule #18 fencing)
__device__ __forceinline__ void bar_sync() {
    __builtin_amdgcn_sched_barrier(0);
    asm volatile("s_waitcnt lgkmcnt(0)" ::: "memory");
    __builtin_amdgcn_s_barrier();
    __builtin_amdgcn_sched_barrier(0);
}

// prep: Qp[c][j] = (W1q+W1d)[c][j]; AbT[j][c] = (W1k-W1d)[c][j];
//       PT[j][c] = W1prod[c][j];    W2t[h2][k] = bf16(W2[k][h2])
__global__ void prep_kernel(const float* __restrict__ W1, const float* __restrict__ W2,
                            float* __restrict__ Qp, float* __restrict__ AbT,
                            float* __restrict__ PT, __bf16* __restrict__ W2t) {
    int tid = blockIdx.x * blockDim.x + threadIdx.x;
    if (tid < 64 * NH1) {
        int c = tid >> 7, j = tid & 127;
        Qp[tid] = W1[c * NH1 + j] + W1[(128 + c) * NH1 + j];
        int jj = tid >> 6, cc = tid & 63;
        AbT[tid] = W1[(64 + cc) * NH1 + jj] - W1[(128 + cc) * NH1 + jj];
        PT[tid]  = W1[(192 + cc) * NH1 + jj];
        int j2 = tid >> 7, k = tid & 127;
        W2t[tid] = (__bf16)W2[k * NH2 + j2];
    }
}

// LDS pool (30976 B; double K, double H1 -> ONE barrier per tile):
//  [0,     4608)  KHI0[32][72] bf16   (aliased by SCORES[224] f32 after main loop)
//  [4608,  9216)  KHI1[32][72] bf16
//  [9216, 17920)  H10 [32][136] bf16  (aliased by REDS[16][72] f32 in epilogue)
//  [17920,26624)  H11 [32][136] bf16
//  [26624,30208)  SP  [4][224] f32
//  [30208,30464)  QS  [64] f32
//  [30464,30976)  QHS [128] f32
__global__ __launch_bounds__(256, 4)
void attn_main(const float* __restrict__ query, const float* __restrict__ key,
               const float* __restrict__ value, const int* __restrict__ mask,
               const float* __restrict__ b1, const float* __restrict__ b2,
               const float* __restrict__ Wo,
               const float* __restrict__ Qp, const float* __restrict__ AbT,
               const float* __restrict__ PT, const __bf16* __restrict__ W2t,
               float* __restrict__ out)
{
    __shared__ __align__(16) char smem[30976];
    auto KHI0 = (__bf16(*)[72])(smem);
    auto KHI1 = (__bf16(*)[72])(smem + 4608);
    auto H10  = (__bf16(*)[136])(smem + 9216);
    auto H11  = (__bf16(*)[136])(smem + 17920);
    auto SP   = (float(*)[NTP])(smem + 26624);
    float* QS  = (float*)(smem + 30208);
    float* QHS = (float*)(smem + 30464);
    float* SCORES = (float*)(smem);            // alias KHI0 (dead after main loop)
    auto REDS = (float(*)[72])(smem + 9216);   // alias H10  (dead after main loop)

    const int b = blockIdx.x;
    const int tid = threadIdx.x;
    const int lane = tid & 63;
    const int wave = tid >> 6;
    const int jn = lane & 15;
    const int g4 = lane >> 4;
    const int g8 = g4 * 8;

    // ---- k-tile staging: coalesced loads, depth-2 register prefetch ----
    const int r_st = tid >> 3;            // row 0..31
    const int c0   = (tid & 7) * 8;       // col 0..56
    const float* kp_base = key + (size_t)b * NT * ND + c0;
    float4 pf[2][2];                      // [tile&1][half]; static indices post-unroll

    {   // issue k(0), k(1) immediately: in flight across the whole prologue
        const float* kp0 = kp_base + (size_t)r_st * ND;
        pf[0][0] = *(const float4*)(kp0);
        pf[0][1] = *(const float4*)(kp0 + 4);
        const float* kp1 = kp_base + (size_t)(32 + r_st) * ND;
        pf[1][0] = *(const float4*)(kp1);
        pf[1][1] = *(const float4*)(kp1 + 4);
    }

    if (tid < ND) QS[tid] = query[(size_t)b * ND + tid];
    int mk = 0;
    if (tid < NT) mk = mask[(size_t)b * NT + tid];
    bar_sync();                            // QS visible

    // qh = b1 + q.(W1q+W1d), 4-way split accumulators
    if (tid < NH1) {
        float a0 = 0.f, a1 = 0.f, a2 = 0.f, a3 = 0.f;
        #pragma unroll
        for (int c = 0; c < ND; c += 4) {
            a0 = fmaf(QS[c],     Qp[c * NH1 + tid],       a0);
            a1 = fmaf(QS[c + 1], Qp[(c + 1) * NH1 + tid], a1);
            a2 = fmaf(QS[c + 2], Qp[(c + 2) * NH1 + tid], a2);
            a3 = fmaf(QS[c + 3], Qp[(c + 3) * NH1 + tid], a3);
        }
        QHS[tid] = b1[tid] + ((a0 + a1) + (a2 + a3));
    }

    // GEMM1 A-frags (swapped): A[j][c] = B_b[c][j] = AbT[j][c] + q[c]*PT[j][c],
    // bf16 hi only (h1 is bf16-quantized at the LDS store anyway).
    bf16x8 g1_b[2][2];
    const int jown = wave * 32;
    #pragma unroll
    for (int n = 0; n < 2; ++n) {
        const int j = jown + n * 16 + jn;
        #pragma unroll
        for (int kk = 0; kk < 2; ++kk) {
            const float* ab = AbT + j * ND + kk * 32 + g8;
            const float* pt = PT  + j * ND + kk * 32 + g8;
            float4 a0 = *(const float4*)ab, a1 = *(const float4*)(ab + 4);
            float4 p0 = *(const float4*)pt, p1 = *(const float4*)(pt + 4);
            const float va[8] = {a0.x,a0.y,a0.z,a0.w,a1.x,a1.y,a1.z,a1.w};
            const float vp[8] = {p0.x,p0.y,p0.z,p0.w,p1.x,p1.y,p1.z,p1.w};
            BF8u vh;
            #pragma unroll
            for (int e = 0; e < 8; ++e) {
                const int c = kk * 32 + g8 + e;
                vh.b[e] = (__bf16)fmaf(QS[c], vp[e], va[e]);
            }
            g1_b[n][kk] = vh.v;
        }
    }
    // GEMM2 B-frags (plain bf16 W2t)
    bf16x8 g2_w[4];
    {
        const int j2 = wave * 16 + jn;
        #pragma unroll
        for (int kk = 0; kk < 4; ++kk)
            g2_w[kk] = *(const bf16x8*)(W2t + j2 * NH1 + kk * 32 + g8);
    }
    bar_sync();                            // QHS visible

    // per-lane qh for the swapped C-layout: j = jown + n*16 + g4*4 + r
    float qh4[2][4];
    {
        const float4 qa = *(const float4*)(QHS + jown + g4 * 4);
        const float4 qb = *(const float4*)(QHS + jown + 16 + g4 * 4);
        qh4[0][0] = qa.x; qh4[0][1] = qa.y; qh4[0][2] = qa.z; qh4[0][3] = qa.w;
        qh4[1][0] = qb.x; qh4[1][1] = qb.y; qh4[1][2] = qb.z; qh4[1][3] = qb.w;
    }
    const float b2j = b2[wave * 16 + jn];
    const float woj = Wo[wave * 16 + jn];

    // ---- ONE-barrier 3-stage pipelined loop (double K, double H1) ----
    // region R(ti), ti = 0..NTILES+1:
    //   stage k(ti)   -> K[ti&1]          (consumed next region)
    //   issue k(ti+2) -> pf[ti&1]         (the slot just freed)
    //   GEMM1(ti-1): read K[(ti-1)&1] -> accc -> publish h1(ti-1) -> H1[(ti-1)&1]
    //   GEMM2(ti-2): read H1[ti&1] -> score -> SP
    //   bar (skipped on the last region)
    // Hazard audit: every K[b]/H1[b] write-read and read-write pair is
    // separated by >=1 barrier (verified per-buffer; see round-17 notes).
    #pragma unroll
    for (int ti = 0; ti <= NTILES + 1; ++ti) {
        if (ti < NTILES) {                 // stage k(ti) -> K[ti&1]
            __bf16 (*KW)[72] = (ti & 1) ? KHI1 : KHI0;
            const int bi = ti & 1;
            const float vals[8] = {pf[bi][0].x, pf[bi][0].y, pf[bi][0].z, pf[bi][0].w,
                                   pf[bi][1].x, pf[bi][1].y, pf[bi][1].z, pf[bi][1].w};
            BF8u ph;
            #pragma unroll
            for (int i = 0; i < 8; ++i) ph.b[i] = (__bf16)vals[i];
            *(uint4*)(&KW[r_st][c0]) = ph.u4;
        }
        if (ti + 2 < NTILES) {             // issue k(ti+2) into the freed slot
            const int bi = ti & 1;
            int t = (ti + 2) * 32 + r_st;
            t = t < NT ? t : NT - 1;
            const float* kp = kp_base + (size_t)t * ND;
            pf[bi][0] = *(const float4*)(kp);
            pf[bi][1] = *(const float4*)(kp + 4);
        }
        if (ti >= 1 && ti <= NTILES) {     // GEMM1(ti-1) + publish h1(ti-1)
            const int tp = ti - 1;
            __bf16 (*KR)[72]  = (tp & 1) ? KHI1 : KHI0;
            __bf16 (*H1W)[136] = (tp & 1) ? H11 : H10;
            f32x4 accc[2][2];
            #pragma unroll
            for (int mt = 0; mt < 2; ++mt) {
                const int arow = mt * 16 + jn;
                const bf16x8 k0 = *(const bf16x8*)(&KR[arow][g8]);
                const bf16x8 k1 = *(const bf16x8*)(&KR[arow][32 + g8]);
                #pragma unroll
                for (int n = 0; n < 2; ++n) {
                    f32x4 ac = {0.f, 0.f, 0.f, 0.f};
                    ac = MFMA16(g1_b[n][0], k0, ac);
                    ac = MFMA16(g1_b[n][1], k1, ac);
                    accc[mt][n] = ac;
                }
            }
            #pragma unroll
            for (int mt = 0; mt < 2; ++mt) {
                const int trow = mt * 16 + jn;
                #pragma unroll
                for (int n = 0; n < 2; ++n) {
                    BF4u pk;
                    #pragma unroll
                    for (int r = 0; r < 4; ++r)
                        pk.b[r] = (__bf16)fmaxf(accc[mt][n][r] + qh4[n][r], 0.f);
                    *(uint2*)(&H1W[trow][jown + n * 16 + g4 * 4]) = pk.u2;
                }
            }
        }
        if (ti >= 2) {                     // GEMM2(ti-2) + score -> SP
            const int tq = ti - 2;
            __bf16 (*H1R)[136] = (tq & 1) ? H11 : H10;
            const int t0 = tq * 32;
            #pragma unroll
            for (int mt = 0; mt < 2; ++mt) {
                const int arow = mt * 16 + jn;
                const bf16x8 h0v = *(const bf16x8*)(&H1R[arow][g8]);
                const bf16x8 h1v = *(const bf16x8*)(&H1R[arow][32 + g8]);
                const bf16x8 h2v = *(const bf16x8*)(&H1R[arow][64 + g8]);
                const bf16x8 h3v = *(const bf16x8*)(&H1R[arow][96 + g8]);
                f32x4 cA = {0.f,0.f,0.f,0.f}, cB = {0.f,0.f,0.f,0.f};
                cA = MFMA16(h0v, g2_w[0], cA);
                cB = MFMA16(h1v, g2_w[1], cB);
                cA = MFMA16(h2v, g2_w[2], cA);
                cB = MFMA16(h3v, g2_w[3], cB);
                #pragma unroll
                for (int r = 0; r < 4; ++r) {
                    float v = fmaxf(cA[r] + cB[r] + b2j, 0.f) * woj;
                    v = row_ror_add<8>(v);
                    v = row_ror_add<4>(v);
                    v = row_ror_add<2>(v);
                    v = row_ror_add<1>(v);
                    if (jn == 0) SP[wave][t0 + mt * 16 + g4 * 4 + r] = v;
                }
            }
        }
        if (ti <= NTILES) bar_sync();      // one barrier per region (none after last)
    }

    // ---- V prefetch (first two rows/thread) — survives the raw barriers ----
    const int tg = tid >> 4;
    const int dq = tid & 15;
    const float* vbase = value + (size_t)b * NT * ND + dq * 4;
    const float4 vv0 = *(const float4*)(vbase + (size_t)tg * ND);
    const float4 vv1 = *(const float4*)(vbase + (size_t)(tg + 16) * ND);

    bar_sync();                            // SP(6) from R(8) visible; K/H1 dead

    // ---- softmax numerator (no max-sub: |s| small, fp32 exp safe) ----
    if (tid < NTP) {
        const float sc = SP[0][tid] + SP[1][tid] + SP[2][tid] + SP[3][tid];
        SCORES[tid] = (tid < NT && mk != 0) ? __expf(sc) : 0.f;
    }
    bar_sync();                            // SCORES ready

    // ---- out = (e @ V) / sum(e), denominator fused ----
    {
        const float e0 = SCORES[tg], e1 = SCORES[tg + 16];
        float oa0 = fmaf(e1, vv1.x, e0 * vv0.x);
        float oa1 = fmaf(e1, vv1.y, e0 * vv0.y);
        float oa2 = fmaf(e1, vv1.z, e0 * vv0.z);
        float oa3 = fmaf(e1, vv1.w, e0 * vv0.w);
        float den = e0 + e1;
        #pragma unroll 4
        for (int t = tg + 32; t < NT; t += 16) {
            const float e = SCORES[t];
            const float4 v4 = *(const float4*)(vbase + (size_t)t * ND);
            oa0 = fmaf(e, v4.x, oa0); oa1 = fmaf(e, v4.y, oa1);
            oa2 = fmaf(e, v4.z, oa2); oa3 = fmaf(e, v4.w, oa3);
            den += e;
        }
        REDS[tg][dq*4+0] = oa0; REDS[tg][dq*4+1] = oa1;
        REDS[tg][dq*4+2] = oa2; REDS[tg][dq*4+3] = oa3;
        if (dq == 0) REDS[tg][64] = den;
    }
    bar_sync();

    if (tid < ND) {
        float s = 0.f, den = 0.f;
        #pragma unroll
        for (int g = 0; g < 16; ++g) { s += REDS[g][tid]; den += REDS[g][64]; }
        out[(size_t)b * ND + tid] = s / den;
    }
}

extern "C" void kernel_launch(void* const* d_in, const int* in_sizes, int n_in,
                              void* d_out, int out_size, void* d_ws, size_t ws_size,
                              hipStream_t stream) {
    const float* query = (const float*)d_in[0];
    const float* key   = (const float*)d_in[1];
    const float* value = (const float*)d_in[2];
    const int*   maskp = (const int*)d_in[3];
    const float* W1    = (const float*)d_in[4];
    const float* b1    = (const float*)d_in[5];
    const float* W2    = (const float*)d_in[6];
    const float* b2    = (const float*)d_in[7];
    const float* Wo    = (const float*)d_in[8];
    float* out = (float*)d_out;

    float* Qp  = (float*)d_ws;                 // 64*128 f32
    float* AbT = Qp + 64 * NH1;                // 128*64 f32
    float* PT  = AbT + NH1 * ND;               // 128*64 f32
    __bf16* W2t = (__bf16*)(PT + NH1 * ND);    // 64*128 bf16

    prep_kernel<<<32, 256, 0, stream>>>(W1, W2, Qp, AbT, PT, W2t);
    attn_main<<<NB, 256, 0, stream>>>(query, key, value, maskp, b1, b2, Wo,
                                      Qp, AbT, PT, W2t, out);
}